// Round 1
// baseline (262.310 us; speedup 1.0000x reference)
//
#include <hip/hip_runtime.h>

// dense_image_warp: out[b,h,w,c] = bilinear(img, h - flow[b,h,w,0], w - flow[b,h,w,1])
// tfa semantics: floor clipped to [0, size-2], alpha clipped to [0,1].
// B=8, H=512, W=512, C=16 (fp32). Pixel = 64 B; top row pair [tl|tr] = 128 B contiguous.

constexpr int B = 8;
constexpr int H = 512;
constexpr int W = 512;
constexpr int C = 16;

// 8 lanes per output pixel (an "octet"):
//  - one 128-B contiguous gather for the top row  [tl|tr]  (8 lanes x float4)
//  - one 128-B contiguous gather for the bottom row [bl|br]
//  - flow loaded once per pixel (lane 0 of octet), broadcast via shfl
//  - lanes 0-3 fetch partner (tr/br) chunks via shfl_xor(4), interpolate, store
// vs previous quad scheme this cuts per-pixel L1 line-lookups ~4 -> ~3 and
// flow lane-ops 4 -> 1, attacking the saturated vector-memory request path.
__global__ __launch_bounds__(256) void warp_kernel(
    const float* __restrict__ img,
    const float* __restrict__ flow,
    float* __restrict__ out)
{
    const int tid = blockIdx.x * blockDim.x + threadIdx.x;
    const int p = tid >> 3;        // pixel index in [0, B*H*W)
    const int j = tid & 7;         // lane within octet

    // decompose p -> (b, h, w); W=512 -> 9 bits, H=512 -> 9 bits
    const int w = p & (W - 1);
    const int h = (p >> 9) & (H - 1);
    const int b = p >> 18;

    // flow[b,h,w,{0,1}] — loaded by lane 0 of the octet only, then broadcast.
    float2 f = make_float2(0.0f, 0.0f);
    if (j == 0) {
        f = *reinterpret_cast<const float2*>(flow + 2 * (size_t)p);
    }
    const float fy_flow = __shfl(f.x, 0, 8);
    const float fx_flow = __shfl(f.y, 0, 8);

    const float qy = (float)h - fy_flow;
    const float qx = (float)w - fx_flow;

    float fy = fminf(fmaxf(floorf(qy), 0.0f), (float)(H - 2));
    float fx = fminf(fmaxf(floorf(qx), 0.0f), (float)(W - 2));
    const float ay = fminf(fmaxf(qy - fy, 0.0f), 1.0f);
    const float ax = fminf(fmaxf(qx - fx, 0.0f), 1.0f);
    const int iy = (int)fy;
    const int ix = (int)fx;

    const int rowStride = W * C;  // floats per image row
    // ix <= W-2 guaranteed, so [ix, ix+1] (128 B) stays in-row.
    const float* rowT = img + ((b * H + iy) * W + ix) * C + j * 4;

    // j in 0..3 -> tl chunk j (top) / bl chunk j (bottom)
    // j in 4..7 -> tr chunk j-4      / br chunk j-4
    const float4 top = *reinterpret_cast<const float4*>(rowT);
    const float4 bot = *reinterpret_cast<const float4*>(rowT + rowStride);

    // partner chunks: for lanes j<4 this yields tr/br chunk j
    float4 topo, boto;
    topo.x = __shfl_xor(top.x, 4);
    topo.y = __shfl_xor(top.y, 4);
    topo.z = __shfl_xor(top.z, 4);
    topo.w = __shfl_xor(top.w, 4);
    boto.x = __shfl_xor(bot.x, 4);
    boto.y = __shfl_xor(bot.y, 4);
    boto.z = __shfl_xor(bot.z, 4);
    boto.w = __shfl_xor(bot.w, 4);

    if (j < 4) {
        // tl=top, tr=topo, bl=bot, br=boto — same op order as reference:
        // interp_top = tl + ax*(tr-tl); interp_bottom = bl + ax*(br-bl);
        // out = interp_top + ay*(interp_bottom - interp_top)
        float4 o;
        {
            const float t0 = top.x + ax * (topo.x - top.x);
            const float b0 = bot.x + ax * (boto.x - bot.x);
            o.x = t0 + ay * (b0 - t0);
        }
        {
            const float t1 = top.y + ax * (topo.y - top.y);
            const float b1 = bot.y + ax * (boto.y - bot.y);
            o.y = t1 + ay * (b1 - t1);
        }
        {
            const float t2 = top.z + ax * (topo.z - top.z);
            const float b2 = bot.z + ax * (boto.z - bot.z);
            o.z = t2 + ay * (b2 - t2);
        }
        {
            const float t3 = top.w + ax * (topo.w - top.w);
            const float b3 = bot.w + ax * (boto.w - bot.w);
            o.w = t3 + ay * (b3 - t3);
        }
        *reinterpret_cast<float4*>(out + (size_t)p * C + j * 4) = o;
    }
}

extern "C" void kernel_launch(void* const* d_in, const int* in_sizes, int n_in,
                              void* d_out, int out_size, void* d_ws, size_t ws_size,
                              hipStream_t stream) {
    const float* img  = (const float*)d_in[0];   // [B,H,W,C] fp32
    const float* flow = (const float*)d_in[1];   // [B,H,W,2] fp32
    float* out = (float*)d_out;                  // [B,H,W,C] fp32

    // 8 lanes per pixel: total threads = B*H*W*8 = 16,777,216 -> exact fit
    const int total = B * H * W * 8;
    const int block = 256;
    const int grid = total / block;  // 65536
    warp_kernel<<<grid, block, 0, stream>>>(img, flow, out);
}

// Round 2
// 253.035 us; speedup vs baseline: 1.0367x; 1.0367x over previous
//
#include <hip/hip_runtime.h>

// dense_image_warp: out[b,h,w,c] = bilinear(img, h - flow[b,h,w,0], w - flow[b,h,w,1])
// tfa semantics: floor clipped to [0, size-2], alpha clipped to [0,1].
// B=8, H=512, W=512, C=16 (fp32).
//
// Structure = round-0 winner (92 us): 4 lanes per pixel, each lane handles 4
// channels (float4, 16 B/lane). Consecutive lanes -> consecutive 16 B chunks:
// coalesced stores; each corner gather is one 64 B segment shared by the quad.
//
// Round-2 change: NON-TEMPORAL output stores. Inputs (img+flow = 151 MB) fit in
// the 256 MB L3, but the 128 MB write stream write-allocates and evicts them
// (observed steady-state FETCH_SIZE 86 MB/dispatch ~= the evicted fraction).
// 'nt' stores keep the write stream out of L2/L3 so the gather stays L3-served.

constexpr int B = 8;
constexpr int H = 512;
constexpr int W = 512;
constexpr int C = 16;

typedef float f32x4 __attribute__((ext_vector_type(4)));

__global__ __launch_bounds__(256) void warp_kernel(
    const float* __restrict__ img,
    const float* __restrict__ flow,
    float* __restrict__ out)
{
    const int tid = blockIdx.x * blockDim.x + threadIdx.x;
    const int p  = tid >> 2;          // pixel index in [0, B*H*W)
    const int c0 = (tid & 3) << 2;    // channel offset: 0,4,8,12

    // decompose p -> (b, h, w); W=512 -> 9 bits, H=512 -> 9 bits
    const int w = p & (W - 1);
    const int h = (p >> 9) & (H - 1);
    const int b = p >> 18;

    // flow[b,h,w,{0,1}] — same address across the 4 lanes of a quad (broadcast)
    const float2 f = *reinterpret_cast<const float2*>(flow + 2 * (size_t)p);

    const float qy = (float)h - f.x;
    const float qx = (float)w - f.y;

    const float fy = fminf(fmaxf(floorf(qy), 0.0f), (float)(H - 2));
    const float fx = fminf(fmaxf(floorf(qx), 0.0f), (float)(W - 2));
    const float ay = fminf(fmaxf(qy - fy, 0.0f), 1.0f);
    const float ax = fminf(fmaxf(qx - fx, 0.0f), 1.0f);
    const int iy = (int)fy;
    const int ix = (int)fx;

    const int rowStride = W * C;  // floats per image row
    const float* base = img + ((b * H + iy) * W + ix) * C + c0;

    const f32x4 tl = *reinterpret_cast<const f32x4*>(base);
    const f32x4 tr = *reinterpret_cast<const f32x4*>(base + C);
    const f32x4 bl = *reinterpret_cast<const f32x4*>(base + rowStride);
    const f32x4 br = *reinterpret_cast<const f32x4*>(base + rowStride + C);

    // Same op order as reference (elementwise):
    // interp_top = tl + ax*(tr-tl); interp_bottom = bl + ax*(br-bl);
    // out = interp_top + ay*(interp_bottom - interp_top)
    const f32x4 t  = tl + ax * (tr - tl);
    const f32x4 bo = bl + ax * (br - bl);
    const f32x4 o  = t + ay * (bo - t);

    // Non-temporal store: don't let the 128 MB write stream evict the
    // L3-resident inputs.
    __builtin_nontemporal_store(
        o, reinterpret_cast<f32x4*>(out + (size_t)p * C + c0));
}

extern "C" void kernel_launch(void* const* d_in, const int* in_sizes, int n_in,
                              void* d_out, int out_size, void* d_ws, size_t ws_size,
                              hipStream_t stream) {
    const float* img  = (const float*)d_in[0];   // [B,H,W,C] fp32
    const float* flow = (const float*)d_in[1];   // [B,H,W,2] fp32
    float* out = (float*)d_out;                  // [B,H,W,C] fp32

    // 4 lanes per pixel: total threads = B*H*W*4 = 8,388,608 -> exact fit
    const int total = B * H * W * 4;
    const int block = 256;
    const int grid = total / block;  // 32768
    warp_kernel<<<grid, block, 0, stream>>>(img, flow, out);
}

// Round 3
// 251.505 us; speedup vs baseline: 1.0430x; 1.0061x over previous
//
#include <hip/hip_runtime.h>

// dense_image_warp: out[b,h,w,c] = bilinear(img, h - flow[b,h,w,0], w - flow[b,h,w,1])
// tfa semantics: floor clipped to [0, size-2], alpha clipped to [0,1].
// B=8, H=512, W=512, C=16 (fp32).
//
// Round-3 theory: latency-bound (all pipes idle, 1720 cyc/wave/SIMD for a
// ~46-inst kernel; two serial memory latencies per wave: flow -> gathers).
// Fix: 2 vertically-adjacent pixels per thread. Both flow loads issue
// back-to-back (MLP 2), then all 8 corner gathers (MLP 8), then 2 coalesced
// 1-KB/wave stores. Halves the number of serial-latency exposures per output
// and doubles outstanding misses per wave. Vertical pairing also makes pixel
// h's bottom corners == pixel h+1's top corners when iy1 == iy0+1 (common,
// since flow varies slowly vs 1 px) -> extra L1 hits on the gather.

constexpr int B = 8;
constexpr int H = 512;
constexpr int W = 512;
constexpr int C = 16;

typedef float f32x4 __attribute__((ext_vector_type(4)));

__global__ __launch_bounds__(256) void warp_kernel(
    const float* __restrict__ img,
    const float* __restrict__ flow,
    float* __restrict__ out)
{
    const int tid = blockIdx.x * blockDim.x + threadIdx.x;
    const int g  = tid >> 2;          // vertical pixel-pair index
    const int c0 = (tid & 3) << 2;    // channel offset: 0,4,8,12

    // g -> (b, hh, w) with hh in [0, H/2); pair rows h0 = 2*hh, h0+1
    const int w  = g & (W - 1);
    const int hh = (g >> 9) & (H / 2 - 1);
    const int b  = g >> 17;
    const int h0 = hh << 1;

    const int p0 = (b * H + h0) * W + w;   // pixel (b, h0,   w)
    const int p1 = p0 + W;                 // pixel (b, h0+1, w)

    // Two independent flow loads -> both in flight together.
    const float2 f0 = *reinterpret_cast<const float2*>(flow + 2 * (size_t)p0);
    const float2 f1 = *reinterpret_cast<const float2*>(flow + 2 * (size_t)p1);

    // --- pixel 0 address math ---
    const float qy0 = (float)h0 - f0.x;
    const float qx0 = (float)w  - f0.y;
    const float fy0 = fminf(fmaxf(floorf(qy0), 0.0f), (float)(H - 2));
    const float fx0 = fminf(fmaxf(floorf(qx0), 0.0f), (float)(W - 2));
    const float ay0 = fminf(fmaxf(qy0 - fy0, 0.0f), 1.0f);
    const float ax0 = fminf(fmaxf(qx0 - fx0, 0.0f), 1.0f);
    const int iy0 = (int)fy0;
    const int ix0 = (int)fx0;

    // --- pixel 1 address math ---
    const float qy1 = (float)(h0 + 1) - f1.x;
    const float qx1 = (float)w        - f1.y;
    const float fy1 = fminf(fmaxf(floorf(qy1), 0.0f), (float)(H - 2));
    const float fx1 = fminf(fmaxf(floorf(qx1), 0.0f), (float)(W - 2));
    const float ay1 = fminf(fmaxf(qy1 - fy1, 0.0f), 1.0f);
    const float ax1 = fminf(fmaxf(qx1 - fx1, 0.0f), 1.0f);
    const int iy1 = (int)fy1;
    const int ix1 = (int)fx1;

    const int rowStride = W * C;  // floats per image row
    const float* base0 = img + ((size_t)((b * H + iy0) * W + ix0) * C + c0);
    const float* base1 = img + ((size_t)((b * H + iy1) * W + ix1) * C + c0);

    // 8 independent corner gathers -> all in flight together.
    const f32x4 tl0 = *reinterpret_cast<const f32x4*>(base0);
    const f32x4 tr0 = *reinterpret_cast<const f32x4*>(base0 + C);
    const f32x4 bl0 = *reinterpret_cast<const f32x4*>(base0 + rowStride);
    const f32x4 br0 = *reinterpret_cast<const f32x4*>(base0 + rowStride + C);
    const f32x4 tl1 = *reinterpret_cast<const f32x4*>(base1);
    const f32x4 tr1 = *reinterpret_cast<const f32x4*>(base1 + C);
    const f32x4 bl1 = *reinterpret_cast<const f32x4*>(base1 + rowStride);
    const f32x4 br1 = *reinterpret_cast<const f32x4*>(base1 + rowStride + C);

    // Reference op order, elementwise.
    const f32x4 t0  = tl0 + ax0 * (tr0 - tl0);
    const f32x4 bo0 = bl0 + ax0 * (br0 - bl0);
    const f32x4 o0  = t0 + ay0 * (bo0 - t0);

    const f32x4 t1  = tl1 + ax1 * (tr1 - tl1);
    const f32x4 bo1 = bl1 + ax1 * (br1 - bl1);
    const f32x4 o1  = t1 + ay1 * (bo1 - t1);

    __builtin_nontemporal_store(
        o0, reinterpret_cast<f32x4*>(out + (size_t)p0 * C + c0));
    __builtin_nontemporal_store(
        o1, reinterpret_cast<f32x4*>(out + (size_t)p1 * C + c0));
}

extern "C" void kernel_launch(void* const* d_in, const int* in_sizes, int n_in,
                              void* d_out, int out_size, void* d_ws, size_t ws_size,
                              hipStream_t stream) {
    const float* img  = (const float*)d_in[0];   // [B,H,W,C] fp32
    const float* flow = (const float*)d_in[1];   // [B,H,W,2] fp32
    float* out = (float*)d_out;                  // [B,H,W,C] fp32

    // 2 pixels per thread, 4 lanes per pixel:
    // total threads = B*(H/2)*W*4 = 4,194,304 -> exact fit
    const int total = B * (H / 2) * W * 4;
    const int block = 256;
    const int grid = total / block;  // 16384
    warp_kernel<<<grid, block, 0, stream>>>(img, flow, out);
}